// Round 9
// baseline (1450.295 us; speedup 1.0000x reference)
//
#include <hip/hip_runtime.h>
#include <hip/hip_bf16.h>

// RNN: B=4096, T=1024, H=40, K=41. fp32 compute & state (dtype autodetected).
// Round-9: K-split x4 cooperative design.
//   2048 blocks x 128 thr (2 waves), 2 els/block -> 8 blocks/CU (8 barrier domains).
//   lane: el = lane&1, p = lane>>1 (0..31): kq = p&3 (K-quarter), rg = wv*8+(p>>2) (0..15).
//   Phase A: row j = 5*rg+q (q<5), thread's K-slice = combined[1+10kq .. 1+10kq+9]
//            (kq==0 also handles u-term + bias). 2-level shfl_xor(2),(4) reduction.
//   Phase B: rg<9 -> rows {3rg..3rg+2}; rg>=9 -> rows {27+2(rg-9), +1}; row 40 =
//            output (o-acts, divergent branch for rg15/q1). K-slice = 10kq..10kq+9.
//   Weights register-resident (~95 floats/thread). LDS = sH + sAct only (~1.2 KB).
//   2 barriers/step. Dual-template dtype safety (proven rounds 3-8).

#define B_SZ 4096
#define T_SZ 1024
#define HID  40

typedef unsigned short u16;
typedef unsigned int   u32;

__device__ __forceinline__ float bf2f(u16 v) {
  union { u32 u; float f; } c; c.u = ((u32)v) << 16; return c.f;
}

template <bool BF>
__device__ __forceinline__ float ldg(const void* p, long i) {
  if (BF) return bf2f(((const u16*)p)[i]);
  return ((const float*)p)[i];
}

// Proven rounds 3-8: true-bf16 weights all have |w| <= 1/sqrt(41) ~ 0.156;
// fp32 data read as bf16 halfwords exceeds 0.2 with P ~ 1-1e-10.
__device__ __forceinline__ bool detect_bf16(const void* w) {
  const u16* p = (const u16*)w;
  bool bf = true;
  for (int i = 0; i < 64; ++i) {
    float f = bf2f(p[i]);
    if (!(fabsf(f) <= 0.2f)) bf = false;
  }
  return bf;
}

template <bool BF>
__global__ __launch_bounds__(128, 2)
void rnn_kernel(const void* __restrict__ inp,
                const void* __restrict__ h2h_w1, const void* __restrict__ h2h_b1,
                const void* __restrict__ h2h_w2, const void* __restrict__ h2h_b2,
                const void* __restrict__ h2o_w1, const void* __restrict__ h2o_b1,
                const void* __restrict__ h2o_w2, const void* __restrict__ h2o_b2,
                void* __restrict__ out) {
  __shared__ __align__(16) float sH[2][48];  // [el][k] hidden (bank-clean stride)
  __shared__ __align__(16) float sA[2][88];  // [el][j] j<40 a-acts, 40..79 o-acts

  if (detect_bf16(h2h_w1) != BF) return;  // wrong-dtype instantiation exits

  const int tid  = threadIdx.x;
  const int lane = tid & 63;
  const int wv   = tid >> 6;         // 0..1
  const int el   = lane & 1;
  const int p    = lane >> 1;        // 0..31
  const int kq   = p & 3;            // K-quarter
  const int rg   = wv * 8 + (p >> 2);// 0..15
  const bool k0  = (kq == 0);

  // ---- Phase-A weights: rows j = 5rg+q, K-slice combined[1+10kq .. +9] ----
  float wa[5][10], wu[5], ba[5];
#pragma unroll
  for (int q = 0; q < 5; ++q) {
    const int  j  = 5 * rg + q;
    const bool hh = (j < HID);
    const void* wb1 = hh ? h2h_w1 : h2o_w1;
    const long  jr  = hh ? j : (j - HID);
    wu[q] = k0 ? ldg<BF>(wb1, jr * 41) : 0.f;
    ba[q] = k0 ? ldg<BF>(hh ? h2h_b1 : h2o_b1, jr) : 0.f;
#pragma unroll
    for (int i = 0; i < 10; ++i)
      wa[q][i] = ldg<BF>(wb1, jr * 41 + 1 + 10 * kq + i);
  }
  // ---- Phase-B weights: rg<9 -> 3 rows {3rg..}; rg>=9 -> 2 rows {27+2(rg-9)..} ----
  const int nB = (rg < 9) ? 3 : 2;
  float wb[3][10], bb[3];
  int   rr[3];
#pragma unroll
  for (int q = 0; q < 3; ++q) {
    rr[q] = 0; bb[q] = 0.f;
    if (q < nB) {
      const int r = (rg < 9) ? 3 * rg + q : 27 + 2 * (rg - 9) + q;
      rr[q] = r;
      if (r < HID) {
        bb[q] = k0 ? ldg<BF>(h2h_b2, r) : 0.f;
#pragma unroll
        for (int i = 0; i < 10; ++i)
          wb[q][i] = ldg<BF>(h2h_w2, (long)r * 40 + 10 * kq + i);
      } else {  // r == 40: output row, weights = h2o_w2
        bb[q] = k0 ? ldg<BF>(h2o_b2, 0) : 0.f;
#pragma unroll
        for (int i = 0; i < 10; ++i)
          wb[q][i] = ldg<BF>(h2o_w2, 10 * kq + i);
      }
    }
  }

  for (int i = tid; i < 2 * 48; i += 128) ((float*)sH)[i] = 0.f;
  __syncthreads();

  const int  b    = blockIdx.x * 2 + el;
  const long base = (long)b * T_SZ;
  float u_cur = ldg<BF>(inp, base);

  for (int t = 0; t < T_SZ; ++t) {
    const float u_nxt = (t + 1 < T_SZ) ? ldg<BF>(inp, base + t + 1) : 0.f;

    // ---------- Phase A: layer 1 (80 neurons, K-split x4) ----------
    float2 hv[5];
    {
      const float2* hp = (const float2*)(&sH[el][10 * kq]);
#pragma unroll
      for (int i = 0; i < 5; ++i) hv[i] = hp[i];
    }
    float acc[5];
#pragma unroll
    for (int q = 0; q < 5; ++q) {
      float a = k0 ? fmaf(u_cur, wu[q], ba[q]) : 0.f;
#pragma unroll
      for (int i = 0; i < 5; ++i) {
        a = fmaf(hv[i].x, wa[q][2 * i],     a);
        a = fmaf(hv[i].y, wa[q][2 * i + 1], a);
      }
      acc[q] = a;
    }
#pragma unroll
    for (int q = 0; q < 5; ++q) {
      float tot = acc[q];
      tot += __shfl_xor(tot, 2);
      tot += __shfl_xor(tot, 4);
      if (k0) sA[el][5 * rg + q] = fmaxf(tot, 0.01f * tot);  // LeakyReLU(0.01)
    }
    __syncthreads();   // acts visible; all sH reads done

    // ---------- Phase B: layer 2 (rows 0..39 = hidden, 40 = output) ----------
    float2 av[5];
    {
      const float2* ap = (const float2*)(&sA[el][10 * kq]);
#pragma unroll
      for (int i = 0; i < 5; ++i) av[i] = ap[i];
    }
#pragma unroll
    for (int q = 0; q < 3; ++q) {
      if (q < nB) {
        float a2 = k0 ? bb[q] : 0.f;
        if (rr[q] < HID) {
#pragma unroll
          for (int i = 0; i < 5; ++i) {
            a2 = fmaf(av[i].x, wb[q][2 * i],     a2);
            a2 = fmaf(av[i].y, wb[q][2 * i + 1], a2);
          }
        } else {  // row 40: o-acts (divergent only for rg15, q==1)
          const float2* op = (const float2*)(&sA[el][40 + 10 * kq]);
#pragma unroll
          for (int i = 0; i < 5; ++i) {
            const float2 o2 = op[i];
            a2 = fmaf(o2.x, wb[q][2 * i],     a2);
            a2 = fmaf(o2.y, wb[q][2 * i + 1], a2);
          }
        }
        float tot = a2;
        tot += __shfl_xor(tot, 2);
        tot += __shfl_xor(tot, 4);
        if (k0) {
          if (rr[q] < HID) {
            sH[el][rr[q]] = tot;
          } else {
            if (BF) ((__hip_bfloat16*)out)[base + t] = __float2bfloat16(tot);
            else    ((float*)out)[base + t] = tot;
          }
        }
      }
    }
    __syncthreads();   // sH update + sA reads done before next step

    u_cur = u_nxt;
  }
}

extern "C" void kernel_launch(void* const* d_in, const int* in_sizes, int n_in,
                              void* d_out, int out_size, void* d_ws, size_t ws_size,
                              hipStream_t stream) {
  (void)in_sizes; (void)n_in; (void)out_size; (void)d_ws; (void)ws_size;
  rnn_kernel<false><<<dim3(B_SZ / 2), dim3(128), 0, stream>>>(
      d_in[0], d_in[1], d_in[2], d_in[3], d_in[4],
      d_in[5], d_in[6], d_in[7], d_in[8], d_out);
  rnn_kernel<true><<<dim3(B_SZ / 2), dim3(128), 0, stream>>>(
      d_in[0], d_in[1], d_in[2], d_in[3], d_in[4],
      d_in[5], d_in[6], d_in[7], d_in[8], d_out);
}

// Round 10
// 877.989 us; speedup vs baseline: 1.6518x; 1.6518x over previous
//
#include <hip/hip_runtime.h>
#include <hip/hip_bf16.h>

// RNN: B=4096, T=1024, H=40, K=41. fp32 compute & state (dtype autodetected).
// Round-10: wave-specialized 2-wave blocks, zero wave-divergence, 4 barrier
// domains/CU.
//   1024 blocks x 128 thr (2 waves), 4 els/block -> 4 blocks/CU (8 waves/CU).
//   el = lane&3, worker w = wv*16 + (lane>>2)  (0..31).
//   Wave 0 (w 0..15):  A: 3 rows {3w,3w+1,3w+2} (rows 0..47)
//                      B: w<8 -> row 32+w; w==8 -> row 40 = OUTPUT (o-acts);
//                         w>8 idle.               (163 FMA/thread)
//   Wave 1 (w 16..31): A: 2 rows {48+2(w-16),+1} (rows 48..79)
//                      B: 2 rows {2(w-16),+1} (rows 0..31). (162 FMA/thread)
//   Weights register/AGPR-resident fp32 (~165 floats). LDS = state only.
//   2 barriers/step. Dual-template dtype safety (proven rounds 3-9).

#define B_SZ 4096
#define T_SZ 1024
#define HID  40

typedef unsigned short u16;
typedef unsigned int   u32;

__device__ __forceinline__ float bf2f(u16 v) {
  union { u32 u; float f; } c; c.u = ((u32)v) << 16; return c.f;
}

template <bool BF>
__device__ __forceinline__ float ldg(const void* p, long i) {
  if (BF) return bf2f(((const u16*)p)[i]);
  return ((const float*)p)[i];
}

// Proven rounds 3-9: true-bf16 weights all have |w| <= 1/sqrt(41) ~ 0.156;
// fp32 data read as bf16 halfwords exceeds 0.2 with P ~ 1-1e-10.
__device__ __forceinline__ bool detect_bf16(const void* w) {
  const u16* p = (const u16*)w;
  bool bf = true;
  for (int i = 0; i < 64; ++i) {
    float f = bf2f(p[i]);
    if (!(fabsf(f) <= 0.2f)) bf = false;
  }
  return bf;
}

template <bool BF>
__global__ __launch_bounds__(128, 2)
void rnn_kernel(const void* __restrict__ inp,
                const void* __restrict__ h2h_w1, const void* __restrict__ h2h_b1,
                const void* __restrict__ h2h_w2, const void* __restrict__ h2h_b2,
                const void* __restrict__ h2o_w1, const void* __restrict__ h2o_b1,
                const void* __restrict__ h2o_w2, const void* __restrict__ h2o_b2,
                void* __restrict__ out) {
  __shared__ __align__(16) float sH[4][44];  // [el][k]  (176 B stride, 16B-mult)
  __shared__ __align__(16) float sA[4][84];  // [el][j]  (336 B stride, 16B-mult)

  if (detect_bf16(h2h_w1) != BF) return;  // wrong-dtype instantiation exits

  const int tid  = threadIdx.x;
  const int lane = tid & 63;
  const int wv   = tid >> 6;                // 0..1 (wave-uniform)
  const int el   = lane & 3;
  const int w    = wv * 16 + (lane >> 2);   // 0..31

  // Row maps (coverage: A rows 0..79 exactly once; B rows 0..40 exactly once)
  const int a0 = (wv == 0) ? 3 * w : 48 + 2 * (w - 16);
  const int nA = (wv == 0) ? 3 : 2;
  const int rB = (wv == 0) ? ((w < 8) ? 32 + w : ((w == 8) ? 40 : -1)) : 2 * (w - 16);

  // ---- Load this thread's 4 weight rows into registers (fp32) ----
  float4 w4[4][10];
  float  wu[3] = {0, 0, 0}, ba[3] = {0, 0, 0}, bb[2] = {0, 0};
#pragma unroll
  for (int q = 0; q < 3; ++q) {
    if (q < nA) {
      const int  j  = a0 + q;
      const bool hh = (j < HID);
      const void* wb1 = hh ? h2h_w1 : h2o_w1;
      const long  jr  = hh ? j : (j - HID);
      wu[q] = ldg<BF>(wb1, jr * 41);
      ba[q] = ldg<BF>(hh ? h2h_b1 : h2o_b1, jr);
#pragma unroll
      for (int i = 0; i < 10; ++i) {
        w4[q][i].x = ldg<BF>(wb1, jr * 41 + 1 + 4 * i);
        w4[q][i].y = ldg<BF>(wb1, jr * 41 + 2 + 4 * i);
        w4[q][i].z = ldg<BF>(wb1, jr * 41 + 3 + 4 * i);
        w4[q][i].w = ldg<BF>(wb1, jr * 41 + 4 + 4 * i);
      }
    }
  }
  if (wv == 0) {
    if (rB >= 0) {
      const bool isout = (rB == 40);
      const void* wb2 = isout ? h2o_w2 : h2h_w2;
      const long  rr  = isout ? 0 : rB;
      bb[0] = isout ? ldg<BF>(h2o_b2, 0) : ldg<BF>(h2h_b2, rB);
#pragma unroll
      for (int i = 0; i < 10; ++i) {
        w4[3][i].x = ldg<BF>(wb2, rr * 40 + 4 * i);
        w4[3][i].y = ldg<BF>(wb2, rr * 40 + 4 * i + 1);
        w4[3][i].z = ldg<BF>(wb2, rr * 40 + 4 * i + 2);
        w4[3][i].w = ldg<BF>(wb2, rr * 40 + 4 * i + 3);
      }
    }
  } else {
#pragma unroll
    for (int q = 0; q < 2; ++q) {
      const long r = rB + q;
      bb[q] = ldg<BF>(h2h_b2, r);
#pragma unroll
      for (int i = 0; i < 10; ++i) {
        w4[2 + q][i].x = ldg<BF>(h2h_w2, r * 40 + 4 * i);
        w4[2 + q][i].y = ldg<BF>(h2h_w2, r * 40 + 4 * i + 1);
        w4[2 + q][i].z = ldg<BF>(h2h_w2, r * 40 + 4 * i + 2);
        w4[2 + q][i].w = ldg<BF>(h2h_w2, r * 40 + 4 * i + 3);
      }
    }
  }

  for (int i = tid; i < 4 * 44; i += 128) ((float*)sH)[i] = 0.f;
  __syncthreads();

  const int  b    = blockIdx.x * 4 + el;
  const long base = (long)b * T_SZ;
  float u_cur = ldg<BF>(inp, base);

  for (int t = 0; t < T_SZ; ++t) {
    const float u_nxt = (t + 1 < T_SZ) ? ldg<BF>(inp, base + t + 1) : 0.f;

    // ---------- Phase A: layer 1 (80 neurons) ----------
    float4 hv[10];
    {
      const float4* hp = (const float4*)sH[el];
#pragma unroll
      for (int i = 0; i < 10; ++i) hv[i] = hp[i];
    }
#pragma unroll
    for (int q = 0; q < 3; ++q) {
      if (q < nA) {   // wave-uniform
        float a = fmaf(u_cur, wu[q], ba[q]);
#pragma unroll
        for (int i = 0; i < 10; ++i) {
          a = fmaf(hv[i].x, w4[q][i].x, a);
          a = fmaf(hv[i].y, w4[q][i].y, a);
          a = fmaf(hv[i].z, w4[q][i].z, a);
          a = fmaf(hv[i].w, w4[q][i].w, a);
        }
        sA[el][a0 + q] = fmaxf(a, 0.01f * a);   // LeakyReLU(0.01)
      }
    }
    __syncthreads();   // sA visible; all sH reads done

    // ---------- Phase B: layer 2 (rows 0..39 = hidden, 40 = output) ----------
    if (wv == 1) {     // uniform: 2 rows, a-acts
      float4 av[10];
      {
        const float4* ap = (const float4*)sA[el];
#pragma unroll
        for (int i = 0; i < 10; ++i) av[i] = ap[i];
      }
#pragma unroll
      for (int q = 0; q < 2; ++q) {
        float a2 = bb[q];
#pragma unroll
        for (int i = 0; i < 10; ++i) {
          a2 = fmaf(av[i].x, w4[2 + q][i].x, a2);
          a2 = fmaf(av[i].y, w4[2 + q][i].y, a2);
          a2 = fmaf(av[i].z, w4[2 + q][i].z, a2);
          a2 = fmaf(av[i].w, w4[2 + q][i].w, a2);
        }
        sH[el][rB + q] = a2;
      }
    } else if (rB >= 0) {   // wave 0: one row (32..39) or output row 40
      const float4* ap = (const float4*)(&sA[el][(rB == 40) ? 40 : 0]);
      float a2 = bb[0];
#pragma unroll
      for (int i = 0; i < 10; ++i) {
        const float4 a4 = ap[i];
        a2 = fmaf(a4.x, w4[3][i].x, a2);
        a2 = fmaf(a4.y, w4[3][i].y, a2);
        a2 = fmaf(a4.z, w4[3][i].z, a2);
        a2 = fmaf(a4.w, w4[3][i].w, a2);
      }
      if (rB < HID) {
        sH[el][rB] = a2;
      } else {
        if (BF) ((__hip_bfloat16*)out)[base + t] = __float2bfloat16(a2);
        else    ((float*)out)[base + t] = a2;
      }
    }
    __syncthreads();   // sH update + sA reads done before next step

    u_cur = u_nxt;
  }
}

extern "C" void kernel_launch(void* const* d_in, const int* in_sizes, int n_in,
                              void* d_out, int out_size, void* d_ws, size_t ws_size,
                              hipStream_t stream) {
  (void)in_sizes; (void)n_in; (void)out_size; (void)d_ws; (void)ws_size;
  rnn_kernel<false><<<dim3(B_SZ / 4), dim3(128), 0, stream>>>(
      d_in[0], d_in[1], d_in[2], d_in[3], d_in[4],
      d_in[5], d_in[6], d_in[7], d_in[8], d_out);
  rnn_kernel<true><<<dim3(B_SZ / 4), dim3(128), 0, stream>>>(
      d_in[0], d_in[1], d_in[2], d_in[3], d_in[4],
      d_in[5], d_in[6], d_in[7], d_in[8], d_out);
}